// Round 3
// baseline (940.970 us; speedup 1.0000x reference)
//
#include <hip/hip_runtime.h>
#include <math.h>

// Problem dims
#define TB 16   // batch (tasks)
#define TT 16   // train steps
#define LL 128  // test length
#define XX 256  // x dim
#define HH 512  // hidden
#define YY 256  // y dim

typedef unsigned long long u64;

__device__ __forceinline__ float wred(float v) {
    v += __shfl_xor(v, 32);
    v += __shfl_xor(v, 16);
    v += __shfl_xor(v, 8);
    v += __shfl_xor(v, 4);
    v += __shfl_xor(v, 2);
    v += __shfl_xor(v, 1);
    return v;
}

// ---------------------------------------------------------------------------
// Relaxed device-scope atomics (coherent point, no cache-maintenance fences).
// ---------------------------------------------------------------------------
__device__ __forceinline__ void ast(float* p, float v) {
    __hip_atomic_store(p, v, __ATOMIC_RELAXED, __HIP_MEMORY_SCOPE_AGENT);
}
__device__ __forceinline__ float ald(const float* p) {
    return __hip_atomic_load(p, __ATOMIC_RELAXED, __HIP_MEMORY_SCOPE_AGENT);
}
__device__ __forceinline__ u64 ald8(const u64* p) {
    return __hip_atomic_load(p, __ATOMIC_RELAXED, __HIP_MEMORY_SCOPE_AGENT);
}

// ---------------------------------------------------------------------------
// Split monotonic barrier (16 blocks/task). tb[0]=arrival count, tb[4]=release
// generation. __syncthreads before arrive drains vmcnt for all waves.
// ---------------------------------------------------------------------------
__device__ __forceinline__ void barrier_arrive(unsigned* tb) {
    const unsigned newv = __hip_atomic_fetch_add(&tb[0], 1u, __ATOMIC_RELAXED,
                                                 __HIP_MEMORY_SCOPE_AGENT) + 1u;
    if ((newv & 15u) == 0u)
        __hip_atomic_store(&tb[4], newv >> 4, __ATOMIC_RELAXED,
                           __HIP_MEMORY_SCOPE_AGENT);
}
__device__ __forceinline__ void barrier_wait(unsigned* tb, unsigned n) {
    while (__hip_atomic_load(&tb[4], __ATOMIC_RELAXED,
                             __HIP_MEMORY_SCOPE_AGENT) < n)
        __builtin_amdgcn_s_sleep(1);
}

// ---------------------------------------------------------------------------
// Async weight staging: global [k][r] slice -> linear LDS, 16B/lane.
// LDS dest must be wave-uniform base + lane*16 (m104) -> linear [k][r] layout.
// ---------------------------------------------------------------------------
__device__ __forceinline__ void gl16(const float* g, float* l) {
    __builtin_amdgcn_global_load_lds(
        (const __attribute__((address_space(1))) unsigned int*)g,
        (__attribute__((address_space(3))) unsigned int*)l, 16, 0, 0);
}

__device__ __forceinline__ void stage_w(const float* M, int GLD, int K, int logR,
                                        float* lw) {
    const int tid = threadIdx.x;
    const int w = tid >> 6, lane = tid & 63;
    const int nops = (K << logR) >> 8;      // K*R/256 chunks of 1KB/wave-op
    const int Rm1 = (1 << logR) - 1;
    for (int op = w; op < nops; op += 4) {
        const int f = op * 256 + lane * 4;  // float index in [k][r] linear
        const int k = f >> logR, r = f & Rm1;
        gl16(M + k * GLD + r, lw + op * 256);
    }
}

// ---------------------------------------------------------------------------
// LDS matvec. lw layout [K][R]. R=32: lanes 0-31/32-63 hit banks 0-31 (2-way,
// free). R=16: 4-way on F4 only (accepted).
// ---------------------------------------------------------------------------
template <int K, int R>
__device__ __forceinline__ float mv_lds(const float* lw, const float* sv, float* sp) {
    const int tid = threadIdx.x;
    const int lane = tid & 63, w = tid >> 6;
    if constexpr (R == 32) {
        const int r = tid & 31, j = tid >> 5;   // 8 k-groups
        constexpr int KPG = K >> 3;
        const float* c = lw + (j * KPG) * 32 + r;
        const float* v = sv + j * KPG;
        float a = 0.f;
        #pragma unroll
        for (int k = 0; k < KPG; ++k) a += c[k * 32] * v[k];
        a += __shfl_xor(a, 32);
        if (lane < 32) sp[w * 32 + lane] = a;
        __syncthreads();
        float s2 = 0.f;
        if (tid < 32) s2 = sp[tid] + sp[32 + tid] + sp[64 + tid] + sp[96 + tid];
        return s2;
    } else {                                    // R == 16 (F4)
        const int r = tid & 15, j = tid >> 4;   // 16 k-groups
        constexpr int KPG = K >> 4;
        const float* c = lw + (j * KPG) * 16 + r;
        const float* v = sv + j * KPG;
        float a = 0.f;
        #pragma unroll
        for (int k = 0; k < KPG; ++k) a += c[k * 16] * v[k];
        a += __shfl_xor(a, 16);
        a += __shfl_xor(a, 32);
        if (lane < 16) sp[w * 16 + lane] = a;
        __syncthreads();
        float s2 = 0.f;
        if (tid < 16) s2 = sp[tid] + sp[16 + tid] + sp[32 + tid] + sp[48 + tid];
        return s2;
    }
}

// Sum 16 per-block partials -> s_c[s] = lr*(c[s]+plus1). 64-bit atomic loads.
__device__ __forceinline__ void cload(const float* crd, float plus1, float lr,
                                      float* s_c) {
    const int tid = threadIdx.x;
    if (tid < 128) {
        const int s = tid >> 3, j = tid & 7;
        const u64 u = ald8((const u64*)(crd + s * 16) + j);
        float v = __uint_as_float((unsigned)(u & 0xffffffffu)) +
                  __uint_as_float((unsigned)(u >> 32));
        v += __shfl_xor(v, 1);
        v += __shfl_xor(v, 2);
        v += __shfl_xor(v, 4);
        if (j == 0) s_c[s] = lr * (v + plus1);
    }
}

// Partial dots of fresh slice (sout) against own history rows s <= tmax.
__device__ __forceinline__ void partials32(const float* hist, int base, int tmax,
                                           float* cpw, int blk, const float* sout) {
    const int tid = threadIdx.x;
    const int s2 = tid >> 4, i = tid & 15;
    float pp = 0.f;
    const bool act = (s2 <= tmax);
    if (act) {
        const float2 h = *(const float2*)&hist[s2 * HH + base + 2 * i];
        pp = h.x * sout[2 * i] + h.y * sout[2 * i + 1];
    }
    pp += __shfl_xor(pp, 1);
    pp += __shfl_xor(pp, 2);
    pp += __shfl_xor(pp, 4);
    pp += __shfl_xor(pp, 8);
    if (act && i == 0) ast(&cpw[s2 * 16 + blk], pp);
}

__device__ __forceinline__ void partials16(const float* hist, int base16, int tmax,
                                           float* cpw, int blk, const float* sout) {
    const int tid = threadIdx.x;
    const int s2 = tid >> 4, i = tid & 15;
    float pp = 0.f;
    const bool act = (s2 <= tmax);
    if (act) pp = hist[s2 * YY + base16 + i] * sout[i];
    pp += __shfl_xor(pp, 1);
    pp += __shfl_xor(pp, 2);
    pp += __shfl_xor(pp, 4);
    pp += __shfl_xor(pp, 8);
    if (act && i == 0) ast(&cpw[s2 * 16 + blk], pp);
}

// ---------------------------------------------------------------------------
// Per-task context (scalar fields only; cw/crd swapped per stage).
// ---------------------------------------------------------------------------
struct TC {
    const float *ty, *tg, *b2, *b3;
    float *Z1, *G1, *H1, *H2, *HG, *D1, *D2, *D3, *D4;
    float *cw, *crd;
    unsigned* tb;
    unsigned n;                    // arrivals so far
    float *sv, *sc, *sg, *sout;    // per-task LDS
};

// One stage of one task: wait -> load -> matvec -> epilogue -> partials -> arrive
// MODE: 0=F2 1=F3 2=F4 3=B4 4=B3 5=B2
template <int MODE>
__device__ __forceinline__ void half_stage(TC& c, const float* lw, float* sp,
                                           int t, float lr, int base, int base16,
                                           int blk) {
    const int tid = threadIdx.x;
    if (tid == 0) barrier_wait(c.tb, c.n);
    __syncthreads();

    constexpr float P1 = (MODE == 0 || MODE == 1) ? 1.0f : 0.0f;
    cload(c.crd, P1, lr, c.sc);
    const float* src =
        MODE == 0 ? c.H1 + t * HH :
        MODE == 1 ? c.H2 + t * HH :
        MODE == 2 ? c.HG + t * HH :
        MODE == 3 ? c.D4 + t * YY :
        MODE == 4 ? c.D3 + t * HH : c.D2 + t * HH;
    constexpr int NF = (MODE == 3) ? YY : HH;
    if (tid < (NF >> 1)) {
        const u64 v = ald8((const u64*)src + tid);
        ((u64*)c.sv)[tid] = v;
    }
    if (MODE == 5 && tid < 16 && (t + 1) < TT)
        c.sg[tid] = ald(&c.G1[tid * 16 + (t + 1)]);
    __syncthreads();   // also drains weight staging (vmcnt)

    float sres;
    if constexpr (MODE == 2)      sres = mv_lds<512, 16>(lw, c.sv, sp);
    else if constexpr (MODE == 3) sres = mv_lds<256, 32>(lw, c.sv, sp);
    else                          sres = mv_lds<512, 32>(lw, c.sv, sp);

    if constexpr (MODE == 2) {
        if (tid < 16) {
            const int row = base16 + tid;
            float corr = 0.f;
            for (int s = 0; s < t; ++s) corr += c.D4[s * YY + row] * c.sc[s];
            const float z = sres - corr;
            const float dlg = (z - c.ty[t * YY + row]) * (2.0f / YY);
            ast(&c.D4[t * YY + row], dlg);
            c.sout[tid] = dlg;
        }
    } else {
        if (tid < 32) {
            const int row = base + tid;
            float corr = 0.f;
            if constexpr (MODE == 0) {
                for (int s = 0; s < t; ++s) corr += c.D2[s * HH + row] * c.sc[s];
                float v = sres + c.b2[row] - corr;
                v = fmaxf(v, 0.f);
                ast(&c.H2[t * HH + row], v);
                c.sout[tid] = v;
            } else if constexpr (MODE == 1) {
                for (int s = 0; s < t; ++s) corr += c.D3[s * HH + row] * c.sc[s];
                float v = sres + c.b3[row] - corr;
                v = fmaxf(v, 0.f) * c.tg[t * HH + row];
                ast(&c.HG[t * HH + row], v);
                c.sout[tid] = v;
            } else if constexpr (MODE == 3) {
                for (int s = 0; s < t; ++s) corr += c.HG[s * HH + row] * c.sc[s];
                const float hgt = c.HG[t * HH + row];
                const float v = (sres - corr) * c.tg[t * HH + row] *
                                ((hgt > 0.f) ? 1.f : 0.f);
                ast(&c.D3[t * HH + row], v);
                c.sout[tid] = v;
            } else if constexpr (MODE == 4) {
                for (int s = 0; s < t; ++s) corr += c.H2[s * HH + row] * c.sc[s];
                const float m = (c.H2[t * HH + row] > 0.f) ? 1.f : 0.f;
                const float v = (sres - corr) * m;
                ast(&c.D2[t * HH + row], v);
                c.sout[tid] = v;
            } else {  // MODE 5 (B2 + h1_{t+1})
                for (int s = 0; s < t; ++s) corr += c.H1[s * HH + row] * c.sc[s];
                const float m = (c.H1[t * HH + row] > 0.f) ? 1.f : 0.f;
                const float dz = (sres - corr) * m;
                ast(&c.D1[t * HH + row], dz);
                if (t + 1 < TT) {
                    float cr = dz * c.sg[t];
                    for (int s = 0; s < t; ++s) cr += c.D1[s * HH + row] * c.sg[s];
                    const float z = c.Z1[(t + 1) * HH + row];
                    const float h1n = fmaxf(z - lr * cr, 0.f);
                    ast(&c.H1[(t + 1) * HH + row], h1n);
                    c.sout[tid] = h1n;
                }
            }
        }
    }
    __syncthreads();

    if constexpr (MODE == 0)      partials32(c.H2, base, t - 1, c.cw, blk, c.sout);
    else if constexpr (MODE == 1) partials32(c.HG, base, t - 1, c.cw, blk, c.sout);
    else if constexpr (MODE == 2) partials16(c.D4, base16, t - 1, c.cw, blk, c.sout);
    else if constexpr (MODE == 3) partials32(c.D3, base, t - 1, c.cw, blk, c.sout);
    else if constexpr (MODE == 4) partials32(c.D2, base, t - 1, c.cw, blk, c.sout);
    else partials32(c.H1, base, (t + 1 < TT) ? t : -1, c.cw, blk, c.sout);
    { float* tmp = c.cw; c.cw = c.crd; c.crd = tmp; }
    __syncthreads();   // drains partials stores (all waves)
    if (tid == 0) barrier_arrive(c.tb);
    c.n += 1;
}

// ---------------------------------------------------------------------------
// P0 per task: Z1base (all t), H1[0], Gram G1 (blk 15).
// ---------------------------------------------------------------------------
__device__ __forceinline__ void p0_task(const float* txb, const float* WT1,
                                        const float* b1v, float* Z1b, float* G1b,
                                        float* H1b, int base, int blk,
                                        float* s_x, float* spz) {
    const int tid = threadIdx.x;
    const int lane = tid & 63, w = tid >> 6;
    {
        const float4* src = (const float4*)txb;   // 1024 float4
        #pragma unroll
        for (int q = 0; q < 4; ++q) {
            const int idx = q * 256 + tid;
            const int tt = idx >> 6, k4 = idx & 63;
            *(float4*)&s_x[tt * 260 + k4 * 4] = src[idx];
        }
    }
    __syncthreads();
    {
        const int r = tid & 31, j = tid >> 5;
        float acc[16];
        #pragma unroll
        for (int tt = 0; tt < 16; ++tt) acc[tt] = 0.f;
        const float* col = WT1 + (j * 32) * HH + base + r;
        #pragma unroll 4
        for (int kk = 0; kk < 32; ++kk) {
            const float wv = col[kk * HH];
            const int k = j * 32 + kk;
            #pragma unroll
            for (int tt = 0; tt < 16; ++tt) acc[tt] += wv * s_x[tt * 260 + k];
        }
        #pragma unroll
        for (int tt = 0; tt < 16; ++tt) {
            float a = acc[tt] + __shfl_xor(acc[tt], 32);
            if (lane < 32) spz[w * 544 + lane * 17 + tt] = a;
        }
        __syncthreads();
        const int rr = tid & 31, tp = tid >> 5;
        #pragma unroll
        for (int q = 0; q < 2; ++q) {
            const int tt = tp * 2 + q;
            const int row = base + rr;
            float v = spz[rr * 17 + tt] + spz[544 + rr * 17 + tt] +
                      spz[1088 + rr * 17 + tt] + spz[1632 + rr * 17 + tt];
            v += b1v[row];
            Z1b[tt * HH + row] = v;
            if (tt == 0) ast(&H1b[row], fmaxf(v, 0.f));
        }
    }
    if (blk == 15) {
        const int ss = tid >> 4, uu = tid & 15;
        float a = 0.f;
        for (int k = 0; k < 256; ++k) a += s_x[ss * 260 + k] * s_x[uu * 260 + k];
        ast(&G1b[ss * 16 + uu], a + 1.0f);
    }
    __syncthreads();   // s_x/spz reuse by next task
}

// ---------------------------------------------------------------------------
// Transpose W1..W4 (64x64 tiles), zero barrier flags, write inner_lr output.
// ---------------------------------------------------------------------------
__global__ __launch_bounds__(256) void k_tr(
    const float* __restrict__ W1, const float* __restrict__ W2,
    const float* __restrict__ W3, const float* __restrict__ W4,
    float* __restrict__ WT1, float* __restrict__ WT2,
    float* __restrict__ WT3, float* __restrict__ WT4,
    const float* __restrict__ loglr, float* __restrict__ out,
    unsigned* __restrict__ bars)
{
    const int tid = threadIdx.x;
    int bid = blockIdx.x;
    if (blockIdx.x == 0)
        __hip_atomic_store(&bars[tid], 0u, __ATOMIC_RELAXED, __HIP_MEMORY_SCOPE_AGENT);
    if (blockIdx.x == 0 && tid == 0) out[2048] = expf(loglr[0]);

    const float* src; float* dst; int R, C;
    if (bid < 32)       { src = W1; dst = WT1; R = 512; C = 256; }
    else if (bid < 96)  { src = W2; dst = WT2; R = 512; C = 512; bid -= 32; }
    else if (bid < 160) { src = W3; dst = WT3; R = 512; C = 512; bid -= 96; }
    else                { src = W4; dst = WT4; R = 256; C = 512; bid -= 160; }
    const int tilesC = C >> 6;
    const int i0 = (bid / tilesC) * 64, j0 = (bid % tilesC) * 64;

    __shared__ float sm[64][65];
    #pragma unroll
    for (int rep = 0; rep < 16; ++rep) {
        const int flat = rep * 256 + tid;
        const int r = flat >> 6, c = flat & 63;
        sm[r][c] = src[(i0 + r) * C + j0 + c];
    }
    __syncthreads();
    #pragma unroll
    for (int rep = 0; rep < 16; ++rep) {
        const int flat = rep * 256 + tid;
        const int c = flat >> 6, r = flat & 63;
        dst[(j0 + c) * R + i0 + r] = sm[r][c];
    }
}

// ---------------------------------------------------------------------------
// Persistent inner loop, 2 tasks per block (latency hiding). 128 blocks of 256.
// Per super-stage: [stage weights -> LDS] [A: wait/compute/arrive]
// [B: wait/compute/arrive] -- each barrier wait has one other-task stage of
// slack; weight staging overlaps the polls.
// ---------------------------------------------------------------------------
__global__ __launch_bounds__(256) void k_inner(
    const float* __restrict__ tx, const float* __restrict__ ty, const float* __restrict__ tg,
    const float* __restrict__ b1v, const float* __restrict__ b2v, const float* __restrict__ b3v,
    const float* __restrict__ W2, const float* __restrict__ W3, const float* __restrict__ W4,
    const float* __restrict__ WT1, const float* __restrict__ WT2, const float* __restrict__ WT3,
    const float* __restrict__ WT4, const float* __restrict__ loglr,
    float* __restrict__ Z1, float* __restrict__ G1,
    float* __restrict__ H1, float* __restrict__ H2, float* __restrict__ HG,
    float* __restrict__ D1, float* __restrict__ D2, float* __restrict__ D3, float* __restrict__ D4,
    float* __restrict__ cpart, unsigned* __restrict__ bars)
{
    const int tid = threadIdx.x;
    const int g = blockIdx.x;
    const int q = g >> 4;
    const int bA = 2 * q, bB = 2 * q + 1;
    const int blk = ((g & 7) << 1) | ((g >> 3) & 1);   // XCD-local weight rows
    const int base = blk * 32, base16 = blk * 16;
    const float lr = expf(loglr[0]);

    __shared__ __align__(16) float lw[16384];   // 64KB weight slice (shared A/B)
    __shared__ float s_x[16 * 260];
    __shared__ float spz[2176];
    __shared__ __align__(16) float s_vA[HH];
    __shared__ __align__(16) float s_vB[HH];
    __shared__ float sp[128];
    __shared__ float soutA[32], soutB[32];
    __shared__ float scA[16], scB[16], sgA[16], sgB[16];

    TC A, B;
    A.ty = ty + bA * (TT * YY); A.tg = tg + bA * (TT * HH);
    A.b2 = b2v; A.b3 = b3v;
    A.Z1 = Z1 + bA * (TT * HH); A.G1 = G1 + bA * (TT * TT);
    A.H1 = H1 + bA * (TT * HH); A.H2 = H2 + bA * (TT * HH); A.HG = HG + bA * (TT * HH);
    A.D1 = D1 + bA * (TT * HH); A.D2 = D2 + bA * (TT * HH); A.D3 = D3 + bA * (TT * HH);
    A.D4 = D4 + bA * (TT * YY);
    A.cw = cpart + bA * 256; A.crd = cpart + 4096 + bA * 256;
    A.tb = bars + bA * 16; A.n = 0;
    A.sv = s_vA; A.sc = scA; A.sg = sgA; A.sout = soutA;

    B.ty = ty + bB * (TT * YY); B.tg = tg + bB * (TT * HH);
    B.b2 = b2v; B.b3 = b3v;
    B.Z1 = Z1 + bB * (TT * HH); B.G1 = G1 + bB * (TT * TT);
    B.H1 = H1 + bB * (TT * HH); B.H2 = H2 + bB * (TT * HH); B.HG = HG + bB * (TT * HH);
    B.D1 = D1 + bB * (TT * HH); B.D2 = D2 + bB * (TT * HH); B.D3 = D3 + bB * (TT * HH);
    B.D4 = D4 + bB * (TT * YY);
    B.cw = cpart + bB * 256; B.crd = cpart + 4096 + bB * 256;
    B.tb = bars + bB * 16; B.n = 0;
    B.sv = s_vB; B.sc = scB; B.sg = sgB; B.sout = soutB;

    // ---------------- P0 both tasks ----------------
    p0_task(tx + bA * (TT * XX), WT1, b1v, A.Z1, A.G1, A.H1, base, blk, s_x, spz);
    p0_task(tx + bB * (TT * XX), WT1, b1v, B.Z1, B.G1, B.H1, base, blk, s_x, spz);
    __syncthreads();
    if (tid == 0) { barrier_arrive(A.tb); barrier_arrive(B.tb); }
    A.n = 1; B.n = 1;

    // First stage's weights (overlaps first barrier wait)
    stage_w(WT2 + base, HH, 512, 5, lw);

    // ---------------- 16 SGD steps x 6 stages, 2 tasks interleaved ----------
    #pragma unroll 1
    for (int t = 0; t < TT; ++t) {
        half_stage<0>(A, lw, sp, t, lr, base, base16, blk);
        half_stage<0>(B, lw, sp, t, lr, base, base16, blk);
        stage_w(WT3 + base, HH, 512, 5, lw);
        half_stage<1>(A, lw, sp, t, lr, base, base16, blk);
        half_stage<1>(B, lw, sp, t, lr, base, base16, blk);
        stage_w(WT4 + base16, YY, 512, 4, lw);
        half_stage<2>(A, lw, sp, t, lr, base, base16, blk);
        half_stage<2>(B, lw, sp, t, lr, base, base16, blk);
        stage_w(W4 + base, HH, 256, 5, lw);
        half_stage<3>(A, lw, sp, t, lr, base, base16, blk);
        half_stage<3>(B, lw, sp, t, lr, base, base16, blk);
        stage_w(W3 + base, HH, 512, 5, lw);
        half_stage<4>(A, lw, sp, t, lr, base, base16, blk);
        half_stage<4>(B, lw, sp, t, lr, base, base16, blk);
        stage_w(W2 + base, HH, 512, 5, lw);
        half_stage<5>(A, lw, sp, t, lr, base, base16, blk);
        half_stage<5>(B, lw, sp, t, lr, base, base16, blk);
        if (t + 1 < TT) stage_w(WT2 + base, HH, 512, 5, lw);
    }
}

// ---------------------------------------------------------------------------
// Phase-2 inner products: ip[b][s][l] = A[b][s] . (act[b][l] *? tg[b][l]) (+1)
// grid: B*T blocks of 256
// ---------------------------------------------------------------------------
template <int K, bool PLUSONE, bool GATE>
__global__ __launch_bounds__(256) void k_ip(
    const float* __restrict__ A, const float* __restrict__ act,
    const float* __restrict__ tg, float* __restrict__ ip)
{
    const int b = blockIdx.x / TT, s = blockIdx.x % TT;
    const int tid = threadIdx.x, lane = tid & 63, w = tid >> 6;
    constexpr int E = K / 64;

    float ar[E];
    #pragma unroll
    for (int j = 0; j < E; j += 4) {
        const float4 v = *(const float4*)&A[(b * TT + s) * K + lane * E + j];
        ar[j] = v.x; ar[j + 1] = v.y; ar[j + 2] = v.z; ar[j + 3] = v.w;
    }
    for (int l0 = 0; l0 < 32; ++l0) {
        const int l = w * 32 + l0;
        float a = 0.0f;
        #pragma unroll
        for (int j = 0; j < E; j += 4) {
            const float4 v = *(const float4*)&act[((long)b * LL + l) * K + lane * E + j];
            float gx = 1.0f, gy = 1.0f, gz = 1.0f, gw = 1.0f;
            if constexpr (GATE) {
                const float4 g = *(const float4*)&tg[((long)b * LL + l) * K + lane * E + j];
                gx = g.x; gy = g.y; gz = g.z; gw = g.w;
            }
            a += v.x * gx * ar[j] + v.y * gy * ar[j + 1] +
                 v.z * gz * ar[j + 2] + v.w * gw * ar[j + 3];
        }
        a = wred(a);
        if (lane == 0) ip[(b * TT + s) * LL + l] = a + (PLUSONE ? 1.0f : 0.0f);
    }
}

// ---------------------------------------------------------------------------
// Phase-2 layer: out[b][l][n] = post( W@act + bias - lr*sum_s D[s][n]*ip[s][l] )
// ---------------------------------------------------------------------------
template <int K, int OUT, bool RELU, bool BIAS, bool GATEIN>
__global__ __launch_bounds__(256) void k_layer(
    const float* __restrict__ W, const float* __restrict__ bias,
    const float* __restrict__ act, const float* __restrict__ tg,
    const float* __restrict__ Dl, const float* __restrict__ ip,
    float* __restrict__ outp, const float* __restrict__ loglr)
{
    constexpr int NC = OUT / 64;
    const int blk = blockIdx.x;
    const int b = blk / (NC * 4);
    const int rem = blk % (NC * 4);
    const int nc = rem / 4, lc = rem % 4;
    const int base_n = nc * 64, base_l = lc * 32;
    const int tid = threadIdx.x;
    const int tn = tid & 31, tl = tid >> 5;  // tl in 0..7
    const float lr = expf(loglr[0]);

    __shared__ float lw[64][65];
    __shared__ float lx[32][65];
    __shared__ float sD[TT][64];
    __shared__ float sip[TT][32];

    #pragma unroll
    for (int rep = 0; rep < 4; ++rep) {
        const int flat = rep * 256 + tid;
        const int s = flat >> 6, n = flat & 63;
        sD[s][n] = Dl[(b * TT + s) * OUT + base_n + n];
    }
    #pragma unroll
    for (int rep = 0; rep < 2; ++rep) {
        const int flat = rep * 256 + tid;
        const int s = flat >> 5, l = flat & 31;
        sip[s][l] = ip[(b * TT + s) * LL + base_l + l];
    }

    float acc[2][4] = {};
    for (int kc = 0; kc < K; kc += 64) {
        __syncthreads();
        #pragma unroll
        for (int rep = 0; rep < 16; ++rep) {
            const int flat = rep * 256 + tid;
            const int i = flat >> 6, k = flat & 63;
            lw[i][k] = W[(base_n + i) * K + kc + k];
        }
        #pragma unroll
        for (int rep = 0; rep < 8; ++rep) {
            const int flat = rep * 256 + tid;
            const int l = flat >> 6, k = flat & 63;
            float v = act[((long)b * LL + base_l + l) * K + kc + k];
            if constexpr (GATEIN)
                v *= tg[((long)b * LL + base_l + l) * K + kc + k];
            lx[l][k] = v;
        }
        __syncthreads();
        #pragma unroll 4
        for (int k = 0; k < 64; ++k) {
            const float w0 = lw[tn][k], w1 = lw[tn + 32][k];
            const float x0 = lx[tl][k],      x1 = lx[tl + 8][k];
            const float x2 = lx[tl + 16][k], x3 = lx[tl + 24][k];
            acc[0][0] += w0 * x0; acc[0][1] += w0 * x1;
            acc[0][2] += w0 * x2; acc[0][3] += w0 * x3;
            acc[1][0] += w1 * x0; acc[1][1] += w1 * x1;
            acc[1][2] += w1 * x2; acc[1][3] += w1 * x3;
        }
    }

    #pragma unroll
    for (int i = 0; i < 2; ++i) {
        const int n = base_n + tn + i * 32;
        const float bv = BIAS ? bias[n] : 0.0f;
        #pragma unroll
        for (int j = 0; j < 4; ++j) {
            const int l = base_l + tl + j * 8;
            float corr = 0.0f;
            #pragma unroll
            for (int s = 0; s < TT; ++s)
                corr += sD[s][tn + i * 32] * sip[s][tl + j * 8];
            float v = acc[i][j] + bv - lr * corr;
            if constexpr (RELU) v = fmaxf(v, 0.0f);
            outp[((long)b * LL + l) * OUT + n] = v;
        }
    }
}

// ---------------------------------------------------------------------------
// Loss: per (b,l): mean_y (logit-ty)^2 -> loss and evaluation
// ---------------------------------------------------------------------------
__global__ __launch_bounds__(64) void k_loss(
    const float* __restrict__ logit, const float* __restrict__ tey,
    float* __restrict__ loss, float* __restrict__ evalo)
{
    const int idx = blockIdx.x;
    const int lane = threadIdx.x;
    float a = 0.0f;
    #pragma unroll
    for (int j = 0; j < 4; ++j) {
        const float d = logit[(long)idx * YY + lane * 4 + j] -
                        tey[(long)idx * YY + lane * 4 + j];
        a += d * d;
    }
    a = wred(a);
    if (lane == 0) {
        const float v = a * (1.0f / YY);
        loss[idx] = v;
        evalo[idx] = v;
    }
}

// ---------------------------------------------------------------------------
extern "C" void kernel_launch(void* const* d_in, const int* in_sizes, int n_in,
                              void* d_out, int out_size, void* d_ws, size_t ws_size,
                              hipStream_t stream)
{
    const float* tx    = (const float*)d_in[0];   // train_x  [B][T][X]
    const float* ty    = (const float*)d_in[1];   // train_y  [B][T][Y]
    const float* tex   = (const float*)d_in[2];   // test_x   [B][L][X]
    const float* tey   = (const float*)d_in[3];   // test_y   [B][L][Y]
    const float* tg    = (const float*)d_in[4];   // train_gate [B][T][H]
    const float* teg   = (const float*)d_in[5];   // test_gate  [B][L][H]
    const float* W1    = (const float*)d_in[6];
    const float* b1    = (const float*)d_in[7];
    const float* W2    = (const float*)d_in[8];
    const float* b2    = (const float*)d_in[9];
    const float* W3    = (const float*)d_in[10];
    const float* b3    = (const float*)d_in[11];
    const float* W4    = (const float*)d_in[12];
    const float* loglr = (const float*)d_in[13];

    float* out = (float*)d_out;
    float* ws  = (float*)d_ws;

    // workspace layout (floats)
    float* Z1base = ws;                 // 131072
    float* G1     = ws + 131072;        // 4096
    float* H1     = ws + 135168;        // 131072
    float* H2     = ws + 266240;        // 131072
    float* HG     = ws + 397312;        // 131072
    float* D1     = ws + 528384;        // 131072
    float* D2     = ws + 659456;        // 131072
    float* D3     = ws + 790528;        // 131072
    float* D4     = ws + 921600;        // 65536
    float* IP     = ws + 991232;        // 32768
    float* ActA   = ws + 1024000;       // 1048576 (phase-1: holds WT1..WT4)
    float* ActB   = ws + 2072576;       // 1048576
    float* WT1    = ActA;               // [256][512] = 131072
    float* WT2    = ActA + 131072;      // [512][512] = 262144
    float* WT3    = ActA + 393216;      // [512][512] = 262144
    float* WT4    = ActA + 655360;      // [512][256] = 131072
    float* cpart  = ws + 3121152;       // 2 x [16 tasks][16 s][16 blk] = 8192
    unsigned* bars = (unsigned*)(ws + 3129344);  // 16 tasks x 16 uints

    // Transpose weights, zero barriers, emit inner_lr.
    k_tr<<<192, 256, 0, stream>>>(W1, W2, W3, W4, WT1, WT2, WT3, WT4, loglr, out, bars);

    // Entire 16-step MAML inner loop; 2 tasks per block.
    k_inner<<<128, 256, 0, stream>>>(tx, ty, tg, b1, b2, b3, W2, W3, W4,
                                     WT1, WT2, WT3, WT4, loglr,
                                     Z1base, G1, H1, H2, HG, D1, D2, D3, D4,
                                     cpart, bars);

    // ---- Phase 2: test-set forward with final (rank-16-corrected) weights ----
    k_ip<XX, true, false><<<TB * TT, 256, 0, stream>>>(tx, tex, nullptr, IP);
    k_layer<XX, HH, true, true, false><<<TB * 8 * 4, 256, 0, stream>>>(
        W1, b1, tex, nullptr, D1, IP, ActA, loglr);

    k_ip<HH, true, false><<<TB * TT, 256, 0, stream>>>(H1, ActA, nullptr, IP);
    k_layer<HH, HH, true, true, false><<<TB * 8 * 4, 256, 0, stream>>>(
        W2, b2, ActA, nullptr, D2, IP, ActB, loglr);

    k_ip<HH, true, false><<<TB * TT, 256, 0, stream>>>(H2, ActB, nullptr, IP);
    k_layer<HH, HH, true, true, false><<<TB * 8 * 4, 256, 0, stream>>>(
        W3, b3, ActB, nullptr, D3, IP, ActA, loglr);

    k_ip<HH, false, true><<<TB * TT, 256, 0, stream>>>(HG, ActA, teg, IP);
    k_layer<HH, YY, false, false, true><<<TB * 4 * 4, 256, 0, stream>>>(
        W4, nullptr, ActA, teg, D4, IP, out + 4097, loglr);

    k_loss<<<TB * LL, 64, 0, stream>>>(out + 4097, tey, out, out + 2049);
}

// Round 4
// 566.017 us; speedup vs baseline: 1.6624x; 1.6624x over previous
//
#include <hip/hip_runtime.h>
#include <math.h>

// Problem dims
#define TB 16   // batch (tasks)
#define TT 16   // train steps
#define LL 128  // test length
#define XX 256  // x dim
#define HH 512  // hidden
#define YY 256  // y dim

typedef unsigned long long u64;

__device__ __forceinline__ float wred(float v) {
    v += __shfl_xor(v, 32);
    v += __shfl_xor(v, 16);
    v += __shfl_xor(v, 8);
    v += __shfl_xor(v, 4);
    v += __shfl_xor(v, 2);
    v += __shfl_xor(v, 1);
    return v;
}

// ---------------------------------------------------------------------------
// Relaxed device-scope atomics (coherent point, no cache-maintenance fences).
// ---------------------------------------------------------------------------
__device__ __forceinline__ void ast(float* p, float v) {
    __hip_atomic_store(p, v, __ATOMIC_RELAXED, __HIP_MEMORY_SCOPE_AGENT);
}
__device__ __forceinline__ float ald(const float* p) {
    return __hip_atomic_load(p, __ATOMIC_RELAXED, __HIP_MEMORY_SCOPE_AGENT);
}
__device__ __forceinline__ u64 ald8(const u64* p) {
    return __hip_atomic_load(p, __ATOMIC_RELAXED, __HIP_MEMORY_SCOPE_AGENT);
}

// ---------------------------------------------------------------------------
// Counter-poll barrier (16 blocks/task): arrive = fetch_add on tb[0];
// waiters poll the counter itself (no separate release hop). Monotonic.
// __syncthreads before arrive drains vmcnt for all waves (data stores ack'd).
// ---------------------------------------------------------------------------
__device__ __forceinline__ void barrier_arrive(unsigned* tb) {
    __hip_atomic_fetch_add(&tb[0], 1u, __ATOMIC_RELAXED, __HIP_MEMORY_SCOPE_AGENT);
}
__device__ __forceinline__ void barrier_wait(unsigned* tb, unsigned n) {
    while (__hip_atomic_load(&tb[0], __ATOMIC_RELAXED,
                             __HIP_MEMORY_SCOPE_AGENT) < n * 16u)
        __builtin_amdgcn_s_sleep(1);
}

// Sum 16 per-block partials -> s_c[s] = lr*(c[s]+plus1). 64-bit atomic loads.
__device__ __forceinline__ void cload(const float* crd, float plus1, float lr,
                                      float* s_c) {
    const int tid = threadIdx.x;
    if (tid < 128) {
        const int s = tid >> 3, j = tid & 7;
        const u64 u = ald8((const u64*)(crd + s * 16) + j);
        float v = __uint_as_float((unsigned)(u & 0xffffffffu)) +
                  __uint_as_float((unsigned)(u >> 32));
        v += __shfl_xor(v, 1);
        v += __shfl_xor(v, 2);
        v += __shfl_xor(v, 4);
        if (j == 0) s_c[s] = lr * (v + plus1);
    }
}

// Partial dots of fresh slice (sout) against own LDS history rows s <= tmax.
__device__ __forceinline__ void partials32L(const float* hist, int tmax,
                                            float* cpw, int blk, const float* sout) {
    const int tid = threadIdx.x;
    const int s2 = tid >> 4, i = tid & 15;
    float pp = 0.f;
    const bool act = (s2 <= tmax);
    if (act) {
        pp = hist[s2 * 32 + 2 * i] * sout[2 * i] +
             hist[s2 * 32 + 2 * i + 1] * sout[2 * i + 1];
    }
    pp += __shfl_xor(pp, 1);
    pp += __shfl_xor(pp, 2);
    pp += __shfl_xor(pp, 4);
    pp += __shfl_xor(pp, 8);
    if (act && i == 0) ast(&cpw[s2 * 16 + blk], pp);
}

__device__ __forceinline__ void partials16L(const float* hist, int tmax,
                                            float* cpw, int blk, const float* sout) {
    const int tid = threadIdx.x;
    const int s2 = tid >> 4, i = tid & 15;
    float pp = 0.f;
    const bool act = (s2 <= tmax);
    if (act) pp = hist[s2 * 16 + i] * sout[i];
    pp += __shfl_xor(pp, 1);
    pp += __shfl_xor(pp, 2);
    pp += __shfl_xor(pp, 4);
    pp += __shfl_xor(pp, 8);
    if (act && i == 0) ast(&cpw[s2 * 16 + blk], pp);
}

// ---------------------------------------------------------------------------
// One stage. MODE: 0=F2 1=F3 2=F4 3=B4 4=B3 5=B2(+h1_{t+1}).
// Weight slice prefetched to REGISTERS before the barrier wait (static
// schedule -> loads independent of barrier; they complete during the poll).
// All history reads are LDS (block-private slices). Fresh full vector and
// coefficient partials go through relaxed agent atomics (IF).
// ---------------------------------------------------------------------------
template <int MODE>
__device__ __forceinline__ void do_stage(
    int t, unsigned n, float lr, int base, int base16, int blk,
    const float* __restrict__ M, const float* __restrict__ src,
    float* __restrict__ dst, float* __restrict__ dst2,
    const float* __restrict__ tyb, const float* __restrict__ tgb, float rbias,
    unsigned* __restrict__ tb, float* __restrict__ cw, float* __restrict__ crd,
    float* s_v, float* sp, float* sout, float* s_c,
    float* hcorr, float* hpart, float* hself,
    float* hD1v, float* hZ1v, float* sG1v)
{
    const int tid = threadIdx.x;
    constexpr int ROWS = (MODE == 2) ? 16 : 32;
    constexpr int G = 256 / ROWS;
    constexpr int KTOT = (MODE == 3) ? 256 : 512;
    constexpr int KPG = KTOT / G;
    constexpr int LD = (MODE == 2) ? YY : HH;

    const int r = tid & (ROWS - 1);
    const int j = tid / ROWS;

    // ---- weight prefetch (before barrier; overlaps the wait) ----
    const float* col = M + (j * KPG) * LD + r;
    float wreg[KPG];
    #pragma unroll
    for (int k = 0; k < KPG; ++k) wreg[k] = col[k * LD];

    // ---- wait for previous stage (all 16 blocks) ----
    if (tid == 0) barrier_wait(tb, n);
    __syncthreads();

    // ---- stage fresh vector + coefficients (1 IF round trip, parallel) ----
    constexpr float P1 = (MODE == 0 || MODE == 1) ? 1.0f : 0.0f;
    cload(crd, P1, lr, s_c);
    constexpr int NF = (MODE == 3) ? YY : HH;
    if (tid < (NF >> 1)) ((u64*)s_v)[tid] = ald8((const u64*)src + tid);
    __syncthreads();

    // ---- matvec: registers x LDS ----
    float a = 0.f;
    const float* vv = s_v + j * KPG;
    #pragma unroll
    for (int k = 0; k < KPG; ++k) a += wreg[k] * vv[k];
    const int lane = tid & 63, w = tid >> 6;
    float sres = 0.f;
    if constexpr (ROWS == 32) {
        a += __shfl_xor(a, 32);
        if (lane < 32) sp[w * 32 + lane] = a;
        __syncthreads();
        if (tid < 32) sres = sp[tid] + sp[32 + tid] + sp[64 + tid] + sp[96 + tid];
    } else {
        a += __shfl_xor(a, 16);
        a += __shfl_xor(a, 32);
        if (lane < 16) sp[w * 16 + lane] = a;
        __syncthreads();
        if (tid < 16) sres = sp[tid] + sp[16 + tid] + sp[32 + tid] + sp[48 + tid];
    }

    // ---- epilogue (LDS history only) ----
    if (tid < ROWS) {
        float corr = 0.f;
        for (int s = 0; s < t; ++s) corr += hcorr[s * ROWS + tid] * s_c[s];
        if constexpr (MODE == 5) {
            const float dz = (sres - corr) * ((hcorr[t * 32 + tid] > 0.f) ? 1.f : 0.f);
            ast(dst + t * HH + base + tid, dz);
            hD1v[t * 32 + tid] = dz;
            if (t + 1 < TT) {
                float cr = dz * sG1v[t * 16 + (t + 1)];
                for (int s = 0; s < t; ++s)
                    cr += hD1v[s * 32 + tid] * sG1v[s * 16 + (t + 1)];
                const float h1n = fmaxf(hZ1v[(t + 1) * 32 + tid] - lr * cr, 0.f);
                ast(dst2 + (t + 1) * HH + base + tid, h1n);
                hself[(t + 1) * 32 + tid] = h1n;
                sout[tid] = h1n;
            }
        } else {
            float v;
            if constexpr (MODE == 0)
                v = fmaxf(sres + rbias - corr, 0.f);
            else if constexpr (MODE == 1)
                v = fmaxf(sres + rbias - corr, 0.f) * tgb[t * HH + base + tid];
            else if constexpr (MODE == 2)
                v = (sres - corr - tyb[t * YY + base16 + tid]) * (2.0f / YY);
            else if constexpr (MODE == 3)
                v = (sres - corr) * tgb[t * HH + base + tid] *
                    ((hcorr[t * 32 + tid] > 0.f) ? 1.f : 0.f);
            else
                v = (sres - corr) * ((hcorr[t * 32 + tid] > 0.f) ? 1.f : 0.f);
            if constexpr (MODE == 2) ast(dst + t * YY + base16 + tid, v);
            else                     ast(dst + t * HH + base + tid, v);
            hself[t * ROWS + tid] = v;
            sout[tid] = v;
        }
    }
    __syncthreads();

    // ---- partials for next stage's coefficients ----
    const int tmax = (MODE == 5) ? ((t + 1 < TT) ? t : -1) : (t - 1);
    if constexpr (MODE == 2) partials16L(hpart, tmax, cw, blk, sout);
    else                     partials32L(hpart, tmax, cw, blk, sout);
    __syncthreads();   // drains partials stores (all waves)
    if (tid == 0) barrier_arrive(tb);
}

// ---------------------------------------------------------------------------
// Transpose W1..W4 (64x64 tiles), zero barrier flags, write inner_lr output.
// ---------------------------------------------------------------------------
__global__ __launch_bounds__(256) void k_tr(
    const float* __restrict__ W1, const float* __restrict__ W2,
    const float* __restrict__ W3, const float* __restrict__ W4,
    float* __restrict__ WT1, float* __restrict__ WT2,
    float* __restrict__ WT3, float* __restrict__ WT4,
    const float* __restrict__ loglr, float* __restrict__ out,
    unsigned* __restrict__ bars)
{
    const int tid = threadIdx.x;
    int bid = blockIdx.x;
    if (blockIdx.x == 0)
        __hip_atomic_store(&bars[tid], 0u, __ATOMIC_RELAXED, __HIP_MEMORY_SCOPE_AGENT);
    if (blockIdx.x == 0 && tid == 0) out[2048] = expf(loglr[0]);

    const float* src; float* dst; int R, C;
    if (bid < 32)       { src = W1; dst = WT1; R = 512; C = 256; }
    else if (bid < 96)  { src = W2; dst = WT2; R = 512; C = 512; bid -= 32; }
    else if (bid < 160) { src = W3; dst = WT3; R = 512; C = 512; bid -= 96; }
    else                { src = W4; dst = WT4; R = 256; C = 512; bid -= 160; }
    const int tilesC = C >> 6;
    const int i0 = (bid / tilesC) * 64, j0 = (bid % tilesC) * 64;

    __shared__ float sm[64][65];
    #pragma unroll
    for (int rep = 0; rep < 16; ++rep) {
        const int flat = rep * 256 + tid;
        const int r = flat >> 6, c = flat & 63;
        sm[r][c] = src[(i0 + r) * C + j0 + c];
    }
    __syncthreads();
    #pragma unroll
    for (int rep = 0; rep < 16; ++rep) {
        const int flat = rep * 256 + tid;
        const int c = flat >> 6, r = flat & 63;
        dst[(j0 + c) * R + i0 + r] = sm[r][c];
    }
}

// ---------------------------------------------------------------------------
// Persistent inner loop. 256 blocks of 256; 16 blocks/task, 32 rows/block.
// 97 counter-poll barriers per task. History lives in LDS; weights are
// register-prefetched ahead of each barrier.
// ---------------------------------------------------------------------------
__global__ __launch_bounds__(256, 1) void k_inner(
    const float* __restrict__ tx, const float* __restrict__ ty, const float* __restrict__ tg,
    const float* __restrict__ b1v, const float* __restrict__ b2v, const float* __restrict__ b3v,
    const float* __restrict__ W2, const float* __restrict__ W3, const float* __restrict__ W4,
    const float* __restrict__ WT1, const float* __restrict__ WT2, const float* __restrict__ WT3,
    const float* __restrict__ WT4, const float* __restrict__ loglr,
    float* __restrict__ H1, float* __restrict__ H2, float* __restrict__ HG,
    float* __restrict__ D1, float* __restrict__ D2, float* __restrict__ D3, float* __restrict__ D4,
    float* __restrict__ cpart, unsigned* __restrict__ bars)
{
    const int tid = threadIdx.x;
    const int lane = tid & 63, w = tid >> 6;
    const int g = blockIdx.x;
    const int b = g >> 4;
    const int blk = ((g & 7) << 1) | ((g >> 3) & 1);   // XCD-local weight rows
    const int base = blk * 32, base16 = blk * 16;
    const float lr = expf(loglr[0]);
    unsigned* tb = bars + b * 16;

    const float* txb = tx + b * (TT * XX);
    const float* tyb = ty + b * (TT * YY);
    const float* tgb = tg + b * (TT * HH);
    float* H1b = H1 + b * (TT * HH);
    float* H2b = H2 + b * (TT * HH);
    float* HGb = HG + b * (TT * HH);
    float* D1b = D1 + b * (TT * HH);
    float* D2b = D2 + b * (TT * HH);
    float* D3b = D3 + b * (TT * HH);
    float* D4b = D4 + b * (TT * YY);
    float* cw  = cpart + b * 256;          // parity-0 partial buffer [16 s][16 blk]
    float* crd = cpart + 4096 + b * 256;   // parity-1

    __shared__ float s_x[16 * 260];  // P0 only
    __shared__ float spz[2176];      // P0 only
    __shared__ __align__(16) float s_v[HH];
    __shared__ float sp[128];
    __shared__ float sout[32];
    __shared__ float s_c[16];
    // Block-private history (own 32/16-row slices), LDS-resident:
    __shared__ float hH1[TT * 32], hH2[TT * 32], hHG[TT * 32];
    __shared__ float hD1[TT * 32], hD2[TT * 32], hD3[TT * 32];
    __shared__ float hD4[TT * 16];
    __shared__ float hZ1[TT * 32];
    __shared__ float sG1[TT * 16];

    const float rb2 = (tid < 32) ? b2v[base + tid] : 0.f;
    const float rb3 = (tid < 32) ? b3v[base + tid] : 0.f;

    // ---------------- P0: Z1base (LDS), G1 (LDS, replicated), H1[0] ----------
    {
        const float4* src4 = (const float4*)txb;   // 1024 float4
        #pragma unroll
        for (int q = 0; q < 4; ++q) {
            const int idx = q * 256 + tid;
            const int tt = idx >> 6, k4 = idx & 63;
            *(float4*)&s_x[tt * 260 + k4 * 4] = src4[idx];
        }
    }
    __syncthreads();
    {
        const int r = tid & 31, j = tid >> 5;
        float acc[16];
        #pragma unroll
        for (int tt = 0; tt < 16; ++tt) acc[tt] = 0.f;
        const float* col = WT1 + (j * 32) * HH + base + r;
        #pragma unroll 4
        for (int kk = 0; kk < 32; ++kk) {
            const float wv = col[kk * HH];
            const int k = j * 32 + kk;
            #pragma unroll
            for (int tt = 0; tt < 16; ++tt) acc[tt] += wv * s_x[tt * 260 + k];
        }
        #pragma unroll
        for (int tt = 0; tt < 16; ++tt) {
            float a = acc[tt] + __shfl_xor(acc[tt], 32);
            if (lane < 32) spz[w * 544 + lane * 17 + tt] = a;
        }
        __syncthreads();
        const int rr = tid & 31, tp = tid >> 5;
        #pragma unroll
        for (int q = 0; q < 2; ++q) {
            const int tt = tp * 2 + q;
            const int row = base + rr;
            float v = spz[rr * 17 + tt] + spz[544 + rr * 17 + tt] +
                      spz[1088 + rr * 17 + tt] + spz[1632 + rr * 17 + tt];
            v += b1v[row];
            hZ1[tt * 32 + rr] = v;
            if (tt == 0) {
                const float h = fmaxf(v, 0.f);
                hH1[rr] = h;
                ast(&H1b[row], h);
            }
        }
    }
    {   // Gram matrix, replicated per block (kills the G1 IF round trip)
        const int ss = tid >> 4, uu = tid & 15;
        float a = 0.f;
        for (int k = 0; k < 256; ++k) a += s_x[ss * 260 + k] * s_x[uu * 260 + k];
        sG1[ss * 16 + uu] = a + 1.0f;
    }
    __syncthreads();   // drains ast + orders LDS writes
    if (tid == 0) barrier_arrive(tb);

    // ---------------- 16 SGD steps x 6 stages ----------------
    unsigned n = 1;
    #pragma unroll 1
    for (int t = 0; t < TT; ++t) {
        do_stage<0>(t, n++, lr, base, base16, blk, WT2 + base, H1b + t * HH,
                    H2b, nullptr, tyb, tgb, rb2, tb, cw, crd,
                    s_v, sp, sout, s_c, hD2, hH2, hH2, hD1, hZ1, sG1);
        { float* tmp = cw; cw = crd; crd = tmp; }
        do_stage<1>(t, n++, lr, base, base16, blk, WT3 + base, H2b + t * HH,
                    HGb, nullptr, tyb, tgb, rb3, tb, cw, crd,
                    s_v, sp, sout, s_c, hD3, hHG, hHG, hD1, hZ1, sG1);
        { float* tmp = cw; cw = crd; crd = tmp; }
        do_stage<2>(t, n++, lr, base, base16, blk, WT4 + base16, HGb + t * HH,
                    D4b, nullptr, tyb, tgb, 0.f, tb, cw, crd,
                    s_v, sp, sout, s_c, hD4, hD4, hD4, hD1, hZ1, sG1);
        { float* tmp = cw; cw = crd; crd = tmp; }
        do_stage<3>(t, n++, lr, base, base16, blk, W4 + base, D4b + t * YY,
                    D3b, nullptr, tyb, tgb, 0.f, tb, cw, crd,
                    s_v, sp, sout, s_c, hHG, hD3, hD3, hD1, hZ1, sG1);
        { float* tmp = cw; cw = crd; crd = tmp; }
        do_stage<4>(t, n++, lr, base, base16, blk, W3 + base, D3b + t * HH,
                    D2b, nullptr, tyb, tgb, 0.f, tb, cw, crd,
                    s_v, sp, sout, s_c, hH2, hD2, hD2, hD1, hZ1, sG1);
        { float* tmp = cw; cw = crd; crd = tmp; }
        do_stage<5>(t, n++, lr, base, base16, blk, W2 + base, D2b + t * HH,
                    D1b, H1b, tyb, tgb, 0.f, tb, cw, crd,
                    s_v, sp, sout, s_c, hH1, hH1, hH1, hD1, hZ1, sG1);
        { float* tmp = cw; cw = crd; crd = tmp; }
    }
}

// ---------------------------------------------------------------------------
// Phase-2 inner products: ip[b][s][l] = A[b][s] . (act[b][l] *? tg[b][l]) (+1)
// grid: B*T blocks of 256
// ---------------------------------------------------------------------------
template <int K, bool PLUSONE, bool GATE>
__global__ __launch_bounds__(256) void k_ip(
    const float* __restrict__ A, const float* __restrict__ act,
    const float* __restrict__ tg, float* __restrict__ ip)
{
    const int b = blockIdx.x / TT, s = blockIdx.x % TT;
    const int tid = threadIdx.x, lane = tid & 63, w = tid >> 6;
    constexpr int E = K / 64;

    float ar[E];
    #pragma unroll
    for (int j = 0; j < E; j += 4) {
        const float4 v = *(const float4*)&A[(b * TT + s) * K + lane * E + j];
        ar[j] = v.x; ar[j + 1] = v.y; ar[j + 2] = v.z; ar[j + 3] = v.w;
    }
    for (int l0 = 0; l0 < 32; ++l0) {
        const int l = w * 32 + l0;
        float a = 0.0f;
        #pragma unroll
        for (int j = 0; j < E; j += 4) {
            const float4 v = *(const float4*)&act[((long)b * LL + l) * K + lane * E + j];
            float gx = 1.0f, gy = 1.0f, gz = 1.0f, gw = 1.0f;
            if constexpr (GATE) {
                const float4 g = *(const float4*)&tg[((long)b * LL + l) * K + lane * E + j];
                gx = g.x; gy = g.y; gz = g.z; gw = g.w;
            }
            a += v.x * gx * ar[j] + v.y * gy * ar[j + 1] +
                 v.z * gz * ar[j + 2] + v.w * gw * ar[j + 3];
        }
        a = wred(a);
        if (lane == 0) ip[(b * TT + s) * LL + l] = a + (PLUSONE ? 1.0f : 0.0f);
    }
}

// ---------------------------------------------------------------------------
// Phase-2 layer: out[b][l][n] = post( W@act + bias - lr*sum_s D[s][n]*ip[s][l] )
// ---------------------------------------------------------------------------
template <int K, int OUT, bool RELU, bool BIAS, bool GATEIN>
__global__ __launch_bounds__(256) void k_layer(
    const float* __restrict__ W, const float* __restrict__ bias,
    const float* __restrict__ act, const float* __restrict__ tg,
    const float* __restrict__ Dl, const float* __restrict__ ip,
    float* __restrict__ outp, const float* __restrict__ loglr)
{
    constexpr int NC = OUT / 64;
    const int blk = blockIdx.x;
    const int b = blk / (NC * 4);
    const int rem = blk % (NC * 4);
    const int nc = rem / 4, lc = rem % 4;
    const int base_n = nc * 64, base_l = lc * 32;
    const int tid = threadIdx.x;
    const int tn = tid & 31, tl = tid >> 5;  // tl in 0..7
    const float lr = expf(loglr[0]);

    __shared__ float lw[64][65];
    __shared__ float lx[32][65];
    __shared__ float sD[TT][64];
    __shared__ float sip[TT][32];

    #pragma unroll
    for (int rep = 0; rep < 4; ++rep) {
        const int flat = rep * 256 + tid;
        const int s = flat >> 6, n = flat & 63;
        sD[s][n] = Dl[(b * TT + s) * OUT + base_n + n];
    }
    #pragma unroll
    for (int rep = 0; rep < 2; ++rep) {
        const int flat = rep * 256 + tid;
        const int s = flat >> 5, l = flat & 31;
        sip[s][l] = ip[(b * TT + s) * LL + base_l + l];
    }

    float acc[2][4] = {};
    for (int kc = 0; kc < K; kc += 64) {
        __syncthreads();
        #pragma unroll
        for (int rep = 0; rep < 16; ++rep) {
            const int flat = rep * 256 + tid;
            const int i = flat >> 6, k = flat & 63;
            lw[i][k] = W[(base_n + i) * K + kc + k];
        }
        #pragma unroll
        for (int rep = 0; rep < 8; ++rep) {
            const int flat = rep * 256 + tid;
            const int l = flat >> 6, k = flat & 63;
            float v = act[((long)b * LL + base_l + l) * K + kc + k];
            if constexpr (GATEIN)
                v *= tg[((long)b * LL + base_l + l) * K + kc + k];
            lx[l][k] = v;
        }
        __syncthreads();
        #pragma unroll 4
        for (int k = 0; k < 64; ++k) {
            const float w0 = lw[tn][k], w1 = lw[tn + 32][k];
            const float x0 = lx[tl][k],      x1 = lx[tl + 8][k];
            const float x2 = lx[tl + 16][k], x3 = lx[tl + 24][k];
            acc[0][0] += w0 * x0; acc[0][1] += w0 * x1;
            acc[0][2] += w0 * x2; acc[0][3] += w0 * x3;
            acc[1][0] += w1 * x0; acc[1][1] += w1 * x1;
            acc[1][2] += w1 * x2; acc[1][3] += w1 * x3;
        }
    }

    #pragma unroll
    for (int i = 0; i < 2; ++i) {
        const int n = base_n + tn + i * 32;
        const float bv = BIAS ? bias[n] : 0.0f;
        #pragma unroll
        for (int j = 0; j < 4; ++j) {
            const int l = base_l + tl + j * 8;
            float corr = 0.0f;
            #pragma unroll
            for (int s = 0; s < TT; ++s)
                corr += sD[s][tn + i * 32] * sip[s][tl + j * 8];
            float v = acc[i][j] + bv - lr * corr;
            if constexpr (RELU) v = fmaxf(v, 0.0f);
            outp[((long)b * LL + l) * OUT + n] = v;
        }
    }
}

// ---------------------------------------------------------------------------
// Loss: per (b,l): mean_y (logit-ty)^2 -> loss and evaluation
// ---------------------------------------------------------------------------
__global__ __launch_bounds__(64) void k_loss(
    const float* __restrict__ logit, const float* __restrict__ tey,
    float* __restrict__ loss, float* __restrict__ evalo)
{
    const int idx = blockIdx.x;
    const int lane = threadIdx.x;
    float a = 0.0f;
    #pragma unroll
    for (int j = 0; j < 4; ++j) {
        const float d = logit[(long)idx * YY + lane * 4 + j] -
                        tey[(long)idx * YY + lane * 4 + j];
        a += d * d;
    }
    a = wred(a);
    if (lane == 0) {
        const float v = a * (1.0f / YY);
        loss[idx] = v;
        evalo[idx] = v;
    }
}

// ---------------------------------------------------------------------------
extern "C" void kernel_launch(void* const* d_in, const int* in_sizes, int n_in,
                              void* d_out, int out_size, void* d_ws, size_t ws_size,
                              hipStream_t stream)
{
    const float* tx    = (const float*)d_in[0];   // train_x  [B][T][X]
    const float* ty    = (const float*)d_in[1];   // train_y  [B][T][Y]
    const float* tex   = (const float*)d_in[2];   // test_x   [B][L][X]
    const float* tey   = (const float*)d_in[3];   // test_y   [B][L][Y]
    const float* tg    = (const float*)d_in[4];   // train_gate [B][T][H]
    const float* teg   = (const float*)d_in[5];   // test_gate  [B][L][H]
    const float* W1    = (const float*)d_in[6];
    const float* b1    = (const float*)d_in[7];
    const float* W2    = (const float*)d_in[8];
    const float* b2    = (const float*)d_in[9];
    const float* W3    = (const float*)d_in[10];
    const float* b3    = (const float*)d_in[11];
    const float* W4    = (const float*)d_in[12];
    const float* loglr = (const float*)d_in[13];

    float* out = (float*)d_out;
    float* ws  = (float*)d_ws;

    // workspace layout (floats)
    float* H1     = ws + 135168;        // 131072
    float* H2     = ws + 266240;        // 131072
    float* HG     = ws + 397312;        // 131072
    float* D1     = ws + 528384;        // 131072
    float* D2     = ws + 659456;        // 131072
    float* D3     = ws + 790528;        // 131072
    float* D4     = ws + 921600;        // 65536
    float* IP     = ws + 991232;        // 32768
    float* ActA   = ws + 1024000;       // 1048576 (phase-1: holds WT1..WT4)
    float* ActB   = ws + 2072576;       // 1048576
    float* WT1    = ActA;               // [256][512] = 131072
    float* WT2    = ActA + 131072;      // [512][512] = 262144
    float* WT3    = ActA + 393216;      // [512][512] = 262144
    float* WT4    = ActA + 655360;      // [512][256] = 131072
    float* cpart  = ws + 3121152;       // 2 x [16 tasks][16 s][16 blk] = 8192
    unsigned* bars = (unsigned*)(ws + 3129344);  // 16 tasks x 16 uints

    // Transpose weights, zero barriers, emit inner_lr.
    k_tr<<<192, 256, 0, stream>>>(W1, W2, W3, W4, WT1, WT2, WT3, WT4, loglr, out, bars);

    // Entire 16-step MAML inner loop in one persistent kernel.
    k_inner<<<TB * 16, 256, 0, stream>>>(tx, ty, tg, b1, b2, b3, W2, W3, W4,
                                         WT1, WT2, WT3, WT4, loglr,
                                         H1, H2, HG, D1, D2, D3, D4,
                                         cpart, bars);

    // ---- Phase 2: test-set forward with final (rank-16-corrected) weights ----
    k_ip<XX, true, false><<<TB * TT, 256, 0, stream>>>(tx, tex, nullptr, IP);
    k_layer<XX, HH, true, true, false><<<TB * 8 * 4, 256, 0, stream>>>(
        W1, b1, tex, nullptr, D1, IP, ActA, loglr);

    k_ip<HH, true, false><<<TB * TT, 256, 0, stream>>>(H1, ActA, nullptr, IP);
    k_layer<HH, HH, true, true, false><<<TB * 8 * 4, 256, 0, stream>>>(
        W2, b2, ActA, nullptr, D2, IP, ActB, loglr);

    k_ip<HH, true, false><<<TB * TT, 256, 0, stream>>>(H2, ActB, nullptr, IP);
    k_layer<HH, HH, true, true, false><<<TB * 8 * 4, 256, 0, stream>>>(
        W3, b3, ActB, nullptr, D3, IP, ActA, loglr);

    k_ip<HH, false, true><<<TB * TT, 256, 0, stream>>>(HG, ActA, teg, IP);
    k_layer<HH, YY, false, false, true><<<TB * 4 * 4, 256, 0, stream>>>(
        W4, nullptr, ActA, teg, D4, IP, out + 4097, loglr);

    k_loss<<<TB * LL, 64, 0, stream>>>(out + 4097, tey, out, out + 2049);
}